// Round 9
// baseline (266.779 us; speedup 1.0000x reference)
//
#include <hip/hip_runtime.h>
#include <hip/hip_bf16.h>
#include <math.h>

// Problem constants
#define BATCH 8
#define NSEQ  1024
#define DIMM  768
#define NHEAD 12
#define DHEAD 64
#define SCALE 0.125f           // DHEAD^-0.5
#define ROWS  (BATCH * NSEQ)   // 8192

typedef __hip_bfloat16 bf16;
typedef __bf16 bf16x8 __attribute__((ext_vector_type(8)));
typedef float  f32x4  __attribute__((ext_vector_type(4)));

#if __has_builtin(__builtin_amdgcn_global_load_lds)
#define HAVE_GLL 1
typedef __attribute__((address_space(3))) void lds_void_t;
typedef const __attribute__((address_space(1))) void gbl_void_t;
__device__ __forceinline__ void gload16(const void* g, void* l) {
    __builtin_amdgcn_global_load_lds((gbl_void_t*)g, (lds_void_t*)l, 16, 0, 0);
}
#else
#define HAVE_GLL 0
#endif

__device__ __forceinline__ unsigned pk2(float a, float b) {
    union { unsigned u; bf16 h[2]; } x;
    x.h[0] = __float2bfloat16(a);
    x.h[1] = __float2bfloat16(b);
    return x.u;
}

// -------------------------------------------------- fused prep: LN + 2 weight transposes
#define NT_QKV (DIMM / 32 * (3 * DIMM) / 32)   // 24*72 = 1728
#define NT_OUT (DIMM / 32 * DIMM / 32)         // 24*24 = 576

__device__ __forceinline__ void transpose_tile(const float* __restrict__ W,
                                               bf16* __restrict__ Wt,
                                               int K, int N, int n0, int k0,
                                               int tx, int ty, float (*t)[33]) {
#pragma unroll
    for (int i = 0; i < 32; i += 8)
        t[ty + i][tx] = W[(size_t)(k0 + ty + i) * N + n0 + tx];
    __syncthreads();
#pragma unroll
    for (int i = 0; i < 32; i += 8)
        Wt[(size_t)(n0 + ty + i) * K + k0 + tx] = __float2bfloat16(t[tx][ty + i]);
}

__global__ __launch_bounds__(256) void prep_kernel(const float* __restrict__ x,
                                                   const float* __restrict__ g,
                                                   const float* __restrict__ bta,
                                                   bf16* __restrict__ y,
                                                   const float* __restrict__ Wq,
                                                   bf16* __restrict__ WqT,
                                                   const float* __restrict__ Wo,
                                                   bf16* __restrict__ WoT) {
    __shared__ float ps[4], pq[4];
    __shared__ float mean_s, rstd_s;
    __shared__ float t[32][33];
    int bid = blockIdx.x;
    int tid = threadIdx.x;

    if (bid < ROWS) {
        const float* xr = x + (size_t)bid * DIMM;
        float v[3];
        float s = 0.f, sq = 0.f;
#pragma unroll
        for (int i = 0; i < 3; ++i) {
            v[i] = xr[tid + 256 * i];
            s += v[i];
            sq += v[i] * v[i];
        }
#pragma unroll
        for (int off = 32; off >= 1; off >>= 1) {
            s  += __shfl_down(s, off);
            sq += __shfl_down(sq, off);
        }
        int wid = tid >> 6, lane = tid & 63;
        if (lane == 0) { ps[wid] = s; pq[wid] = sq; }
        __syncthreads();
        if (tid == 0) {
            float S = ps[0] + ps[1] + ps[2] + ps[3];
            float Q = pq[0] + pq[1] + pq[2] + pq[3];
            float mean = S * (1.0f / DIMM);
            float var  = Q * (1.0f / DIMM) - mean * mean;
            mean_s = mean;
            rstd_s = rsqrtf(fmaxf(var, 0.f) + 1e-5f);
        }
        __syncthreads();
        float mean = mean_s, rstd = rstd_s;
        bf16* yr = y + (size_t)bid * DIMM;
#pragma unroll
        for (int i = 0; i < 3; ++i) {
            int c = tid + 256 * i;
            yr[c] = __float2bfloat16((v[i] - mean) * rstd * g[c] + bta[c]);
        }
    } else if (bid < ROWS + NT_QKV) {
        int idx = bid - ROWS;
        int tx = tid & 31, ty = tid >> 5;
        int n0 = (idx % (3 * DIMM / 32)) * 32;
        int k0 = (idx / (3 * DIMM / 32)) * 32;
        transpose_tile(Wq, WqT, DIMM, 3 * DIMM, n0, k0, tx, ty, t);
    } else {
        int idx = bid - ROWS - NT_QKV;
        int tx = tid & 31, ty = tid >> 5;
        int n0 = (idx % (DIMM / 32)) * 32;
        int k0 = (idx / (DIMM / 32)) * 32;
        transpose_tile(Wo, WoT, DIMM, DIMM, n0, k0, tx, ty, t);
    }
}

// --------------------------------- bf16 MFMA GEMM (256x128 tile, 512 thr, T3 dbuf)
// C[M,Nn] = A[M,K] @ Bt[Nn,K]^T (+bias). BM=256, BN=128, BK=32, 8 waves (4m x 2n).
// Same proven T3 2-phase discipline as the 128^2 version (stage NEXT via
// global_load_lds before computing CURRENT; ONE barrier per K-iter), but each
// barrier-drain is amortized over 128 MFMAs/block instead of 64, and staging
// drops to 3 gloads/thread. LDS = 48 KB (As 32K + Bs 16K).
template <bool OUT_BF16>
__global__ __launch_bounds__(512) void gemm_mfma(const bf16* __restrict__ A,
                                                 const bf16* __restrict__ Bt,
                                                 const float* __restrict__ bias,
                                                 void* __restrict__ Cv,
                                                 int M, int Nn, int K) {
    __shared__ bf16 As[2][256][32];   // unpadded: lane-linear for global_load_lds
    __shared__ bf16 Bs[2][128][32];
    int tid = threadIdx.x;
    int wave = tid >> 6, lane = tid & 63, quad = lane >> 4, l16 = lane & 15;
    int wm = (wave >> 1) * 64, wn = (wave & 1) * 64;   // 4 m-groups x 2 n-groups
    int m0 = blockIdx.y * 256, n0 = blockIdx.x * 128;

    f32x4 acc[4][4] = {};

#if HAVE_GLL
    // A: 256 rows x 32 cols; thread t stages rows (t>>2) and 128+(t>>2), col8 (t&3).
    // B: 128 rows x 32 cols; thread t stages row (t>>2), col8 (t&3).
    const char* Ag = (const char*)(A  + (size_t)(m0 + (tid >> 2)) * K + (tid & 3) * 8);
    const char* Bg = (const char*)(Bt + (size_t)(n0 + (tid >> 2)) * K + (tid & 3) * 8);
    char* AsB = (char*)&As[0][0][0] + tid * 16;   // == (t>>2)*64 + (t&3)*16
    char* BsB = (char*)&Bs[0][0][0] + tid * 16;
    const size_t radv = (size_t)128 * K * 2;      // +128 rows (A second half)

    // prologue: stage tile 0 into buf 0 (3 gloads/thread)
    gload16(Ag, AsB);
    gload16(Ag + radv, AsB + 8192);
    gload16(Bg, BsB);
    Ag += 64; Bg += 64;               // 32 bf16
    __syncthreads();                  // drains vmcnt -> tile 0 visible

    int cur = 0;
    for (int k0 = 0; k0 < K; k0 += 32) {
        int nxt = cur ^ 1;
        // ---- stage NEXT tile (async) while computing CURRENT
        if (k0 + 32 < K) {
            gload16(Ag, AsB + nxt * 16384);
            gload16(Ag + radv, AsB + nxt * 16384 + 8192);
            gload16(Bg, BsB + nxt * 8192);
            Ag += 64; Bg += 64;
        }
#else
    // fallback: reg staging. A: row tid>>1 (0..255), 32B; B: row tid>>2, 16B.
    int sra = tid >> 1, ska = (tid & 1) * 16;
    int srb = tid >> 2, skb = (tid & 3) * 8;
    const bf16* Ap = A  + (size_t)(m0 + sra) * K + ska;
    const bf16* Bp = Bt + (size_t)(n0 + srb) * K + skb;
    {
        uint4 a0 = *(const uint4*)(Ap);
        uint4 a1 = *(const uint4*)(Ap + 8);
        uint4 b0 = *(const uint4*)(Bp);
        *(uint4*)&As[0][sra][ska]     = a0;
        *(uint4*)&As[0][sra][ska + 8] = a1;
        *(uint4*)&Bs[0][srb][skb]     = b0;
    }
    __syncthreads();
    int cur = 0;
    for (int k0 = 0; k0 < K; k0 += 32) {
        int nxt = cur ^ 1;
        uint4 a0, a1, b0;
        if (k0 + 32 < K) {
            a0 = *(const uint4*)(Ap + k0 + 32);
            a1 = *(const uint4*)(Ap + k0 + 40);
            b0 = *(const uint4*)(Bp + k0 + 32);
        }
#endif
        bf16x8 af[4], bf_[4];
#pragma unroll
        for (int i = 0; i < 4; ++i) {
            af[i]  = *(const bf16x8*)&As[cur][wm + i * 16 + l16][quad * 8];
            bf_[i] = *(const bf16x8*)&Bs[cur][wn + i * 16 + l16][quad * 8];
        }
#pragma unroll
        for (int mi = 0; mi < 4; ++mi)
#pragma unroll
            for (int ni = 0; ni < 4; ++ni)
                acc[mi][ni] = __builtin_amdgcn_mfma_f32_16x16x32_bf16(
                    af[mi], bf_[ni], acc[mi][ni], 0, 0, 0);
#if !HAVE_GLL
        if (k0 + 32 < K) {
            *(uint4*)&As[nxt][sra][ska]     = a0;
            *(uint4*)&As[nxt][sra][ska + 8] = a1;
            *(uint4*)&Bs[nxt][srb][skb]     = b0;
        }
#endif
        __syncthreads();   // next-tile staging drained/visible; cur reads done
        cur = nxt;
    }

    float bv[4] = {0.f, 0.f, 0.f, 0.f};
    if (!OUT_BF16 && bias) {
#pragma unroll
        for (int ni = 0; ni < 4; ++ni) bv[ni] = bias[n0 + wn + ni * 16 + l16];
    }
#pragma unroll
    for (int mi = 0; mi < 4; ++mi)
#pragma unroll
        for (int reg = 0; reg < 4; ++reg) {
            size_t row = m0 + wm + mi * 16 + quad * 4 + reg;
#pragma unroll
            for (int ni = 0; ni < 4; ++ni) {
                int col = n0 + wn + ni * 16 + l16;
                float val = acc[mi][ni][reg] + bv[ni];
                if (OUT_BF16)
                    ((bf16*)Cv)[row * Nn + col] = __float2bfloat16(val);
                else
                    ((float*)Cv)[row * Nn + col] = val;
            }
        }
}

// --------------------------------------- MFMA flash attention (S^T form, dual q-group)
// Byte-identical to R8 (86.5 us): QBLK=128, 256 threads, each wave owns two
// independent 16-row q-groups sharing K/V staging/barriers; rpb loads issued at
// iteration top; bijective XCD swizzle; setprio; T13 defer (THR=8).
// qkv: [ROWS, 2304] bf16. rpb: [NHEAD, NSEQ, NSEQ] fp32. outb: [ROWS, DIMM] bf16.
#define KTILEB (64 * 3 * DIMM * 2)   // bytes per 64-row k-tile step in qkv
#define NBLK   (BATCH * NHEAD * (NSEQ / 128))   // 768

__global__ __launch_bounds__(256, 3) void attn_mfma(const bf16* __restrict__ qkv,
                                                    const float* __restrict__ rpb,
                                                    bf16* __restrict__ outb) {
    __shared__ char KsRaw[2][8192];      // [buf][t*2048 + s*1024 + (quad*16+l16)*16]
    __shared__ unsigned Vt32[2][64][36]; // [buf][d][k-pair dword], XOR-swizzled blocks
    __shared__ bf16 Ps[4][2][16][72];    // per-wave, per-group P (A-layout)

    int tid = threadIdx.x;
    int wave = tid >> 6, lane = tid & 63, quad = lane >> 4, l16 = lane & 15;

    int p   = blockIdx.x;
    int wid = (p & 7) * (NBLK / 8) + (p >> 3);
    int h   = wid >> 6;          // wid / 64
    int rem = wid & 63;
    int b   = rem >> 3;
    int mt  = rem & 7;
    int m0  = mt * 128;

    const bf16* qrowA = qkv + (size_t)(b * NSEQ + m0 + wave * 16 + l16) * (3 * DIMM) + h * DHEAD;
    const bf16* qrowB = qrowA + (size_t)64 * (3 * DIMM);
    bf16x8 qfA0 = *(const bf16x8*)(qrowA + quad * 8);
    bf16x8 qfA1 = *(const bf16x8*)(qrowA + 32 + quad * 8);
    bf16x8 qfB0 = *(const bf16x8*)(qrowB + quad * 8);
    bf16x8 qfB1 = *(const bf16x8*)(qrowB + 32 + quad * 8);

    const float* rpA = rpb + ((size_t)h * NSEQ + (m0 + wave * 16 + l16)) * NSEQ;
    const float* rpB = rpA + (size_t)64 * NSEQ;

#if HAVE_GLL
    const char* kgl = (const char*)(qkv + (size_t)(b * NSEQ + wave * 16 + l16) * (3 * DIMM)
                                    + DIMM + h * DHEAD + quad * 8);
    char* kdst = &KsRaw[0][0] + tid * 16 + wave * 1024;   // +buf*8192, +i*1024
#else
    int ksr = tid >> 2, ksd = (tid & 3) * 16;
    const bf16* kgf = qkv + (size_t)(b * NSEQ + ksr) * (3 * DIMM) + DIMM + h * DHEAD + ksd;
#endif

    int vk = (tid >> 3) * 2;            // 0..62 even
    int vd = (tid & 7) * 8;             // 0..56
    int vkp = tid >> 3;                 // logical dword col (k-pair)
    const bf16* vg = qkv + (size_t)(b * NSEQ + vk) * (3 * DIMM) + 2 * DIMM + h * DHEAD + vd;
    int wblk = (((vkp >> 2) ^ (vd >> 3)) << 2) | (vkp & 3);

    float mA = -INFINITY, lA = 0.f;
    float mB = -INFINITY, lB = 0.f;
    f32x4 accoA[4] = {}, accoB[4] = {};

    // ---------------- preload tile 0
#if HAVE_GLL
    gload16(kgl, kdst);
    gload16(kgl + 64, kdst + 1024);
#endif
    uint4 va = *(const uint4*)(vg);
    uint4 vb = *(const uint4*)(vg + 3 * DIMM);
#if !HAVE_GLL
    {
        uint4 k0v = *(const uint4*)(kgf);
        uint4 k1v = *(const uint4*)(kgf + 8);
        char* d0 = &KsRaw[0][0] + (ksr >> 4) * 2048 + (ksd >> 5) * 1024 + ((((ksd >> 3) & 3) * 16 + (ksr & 15)) * 16);
        *(uint4*)d0 = k0v;
        char* d1 = &KsRaw[0][0] + (ksr >> 4) * 2048 + ((ksd + 8) >> 5) * 1024 + (((((ksd + 8) >> 3) & 3) * 16 + (ksr & 15)) * 16);
        *(uint4*)d1 = k1v;
    }
#endif
    {
        union { uint4 q; unsigned short u[8]; } A_, B_;
        A_.q = va; B_.q = vb;
#pragma unroll
        for (int j = 0; j < 8; ++j)
            Vt32[0][vd + j][wblk] = (unsigned)A_.u[j] | ((unsigned)B_.u[j] << 16);
    }
    __syncthreads();   // drains gll vmcnt + ds writes

    for (int kt = 0; kt < 16; ++kt) {
        int cur = kt & 1, nxt = cur ^ 1;

        // ---- rpb for CURRENT tile, both groups (issued first; vmcnt-covered)
        float4 rvA[4], rvB[4];
        {
            const float* rka = rpA + kt * 64;
            const float* rkb = rpB + kt * 64;
#pragma unroll
            for (int t = 0; t < 4; ++t) {
                rvA[t] = *(const float4*)&rka[t * 16 + quad * 4];
                rvB[t] = *(const float4*)&rkb[t * 16 + quad * 4];
            }
        }

        // ---- prefetch next tile (K -> LDS[nxt] async, V -> regs)
        if (kt + 1 < 16) {
#if HAVE_GLL
            const char* kg2 = kgl + (size_t)(kt + 1) * KTILEB;
            gload16(kg2, kdst + nxt * 8192);
            gload16(kg2 + 64, kdst + nxt * 8192 + 1024);
#endif
            const bf16* v2 = vg + (size_t)(kt + 1) * 64 * (3 * DIMM);
            va = *(const uint4*)(v2);
            vb = *(const uint4*)(v2 + 3 * DIMM);
        }

        // ---- S^T = K Q^T for both groups (K fragments shared)
        f32x4 accsA[4] = {}, accsB[4] = {};
        __builtin_amdgcn_s_setprio(1);
#pragma unroll
        for (int t = 0; t < 4; ++t) {
            const char* kb = &KsRaw[cur][0] + t * 2048 + (quad * 16 + l16) * 16;
            bf16x8 kf0 = *(const bf16x8*)(kb);
            bf16x8 kf1 = *(const bf16x8*)(kb + 1024);
            accsA[t] = __builtin_amdgcn_mfma_f32_16x16x32_bf16(kf0, qfA0, accsA[t], 0, 0, 0);
            accsA[t] = __builtin_amdgcn_mfma_f32_16x16x32_bf16(kf1, qfA1, accsA[t], 0, 0, 0);
            accsB[t] = __builtin_amdgcn_mfma_f32_16x16x32_bf16(kf0, qfB0, accsB[t], 0, 0, 0);
            accsB[t] = __builtin_amdgcn_mfma_f32_16x16x32_bf16(kf1, qfB1, accsB[t], 0, 0, 0);
        }
        __builtin_amdgcn_s_setprio(0);

        // ---- softmax, two independent chains
        float mxA = -INFINITY, mxB = -INFINITY;
        {
            float rbA[4][4] = {{rvA[0].x, rvA[0].y, rvA[0].z, rvA[0].w},
                               {rvA[1].x, rvA[1].y, rvA[1].z, rvA[1].w},
                               {rvA[2].x, rvA[2].y, rvA[2].z, rvA[2].w},
                               {rvA[3].x, rvA[3].y, rvA[3].z, rvA[3].w}};
            float rbB[4][4] = {{rvB[0].x, rvB[0].y, rvB[0].z, rvB[0].w},
                               {rvB[1].x, rvB[1].y, rvB[1].z, rvB[1].w},
                               {rvB[2].x, rvB[2].y, rvB[2].z, rvB[2].w},
                               {rvB[3].x, rvB[3].y, rvB[3].z, rvB[3].w}};
#pragma unroll
            for (int t = 0; t < 4; ++t)
#pragma unroll
                for (int r = 0; r < 4; ++r) {
                    accsA[t][r] = fmaf(accsA[t][r], SCALE, rbA[t][r]);
                    mxA = fmaxf(mxA, accsA[t][r]);
                    accsB[t][r] = fmaf(accsB[t][r], SCALE, rbB[t][r]);
                    mxB = fmaxf(mxB, accsB[t][r]);
                }
        }
        mxA = fmaxf(mxA, __shfl_xor(mxA, 16));
        mxA = fmaxf(mxA, __shfl_xor(mxA, 32));
        mxB = fmaxf(mxB, __shfl_xor(mxB, 16));
        mxB = fmaxf(mxB, __shfl_xor(mxB, 32));

        // ---- T13 defer-rescale per group (wave-uniform; ~never taken)
        if (__any(mxA > mA + 8.0f)) {
            float mn = fmaxf(mA, mxA);
            float alpha = __expf(mA - mn);
            mA = mn;
            lA *= alpha;
            float ab[4];
#pragma unroll
            for (int r = 0; r < 4; ++r) ab[r] = __shfl(alpha, quad * 4 + r);
#pragma unroll
            for (int dt = 0; dt < 4; ++dt)
#pragma unroll
                for (int r = 0; r < 4; ++r) accoA[dt][r] *= ab[r];
        }
        if (__any(mxB > mB + 8.0f)) {
            float mn = fmaxf(mB, mxB);
            float alpha = __expf(mB - mn);
            mB = mn;
            lB *= alpha;
            float ab[4];
#pragma unroll
            for (int r = 0; r < 4; ++r) ab[r] = __shfl(alpha, quad * 4 + r);
#pragma unroll
            for (int dt = 0; dt < 4; ++dt)
#pragma unroll
                for (int r = 0; r < 4; ++r) accoB[dt][r] *= ab[r];
        }

        float sumA = 0.f, sumB = 0.f;
#pragma unroll
        for (int t = 0; t < 4; ++t)
#pragma unroll
            for (int r = 0; r < 4; ++r) {
                float pa = __expf(accsA[t][r] - mA);
                accsA[t][r] = pa;
                sumA += pa;
                float pb = __expf(accsB[t][r] - mB);
                accsB[t][r] = pb;
                sumB += pb;
            }
        sumA += __shfl_xor(sumA, 16);
        sumA += __shfl_xor(sumA, 32);
        sumB += __shfl_xor(sumB, 16);
        sumB += __shfl_xor(sumB, 32);
        lA += sumA;
        lB += sumB;

        // ---- P^T -> Ps for both groups (A-layout: row q=l16, cols k)
#pragma unroll
        for (int t = 0; t < 4; ++t) {
            uint2 wA, wB;
            wA.x = pk2(accsA[t][0], accsA[t][1]);
            wA.y = pk2(accsA[t][2], accsA[t][3]);
            wB.x = pk2(accsB[t][0], accsB[t][1]);
            wB.y = pk2(accsB[t][2], accsB[t][3]);
            *(uint2*)&Ps[wave][0][l16][t * 16 + quad * 4] = wA;
            *(uint2*)&Ps[wave][1][l16][t * 16 + quad * 4] = wB;
        }
        __asm__ volatile("s_waitcnt lgkmcnt(0)" ::: "memory");

        // ---- O += P V for both groups (V fragments shared)
        __builtin_amdgcn_s_setprio(1);
#pragma unroll
        for (int s = 0; s < 2; ++s) {
            bf16x8 pfA = *(const bf16x8*)&Ps[wave][0][l16][s * 32 + quad * 8];
            bf16x8 pfB = *(const bf16x8*)&Ps[wave][1][l16][s * 32 + quad * 8];
#pragma unroll
            for (int dt = 0; dt < 4; ++dt) {
                int row = dt * 16 + l16;
                int sblk = (((s * 4 + quad) ^ ((row >> 3) & 7)) << 2);
                bf16x8 vf = *(const bf16x8*)&Vt32[cur][row][sblk];
                accoA[dt] = __builtin_amdgcn_mfma_f32_16x16x32_bf16(pfA, vf, accoA[dt], 0, 0, 0);
                accoB[dt] = __builtin_amdgcn_mfma_f32_16x16x32_bf16(pfB, vf, accoB[dt], 0, 0, 0);
            }
        }
        __builtin_amdgcn_s_setprio(0);

        // ---- stage prefetched V into Vt[nxt]
        if (kt + 1 < 16) {
            union { uint4 q; unsigned short u[8]; } A_, B_;
            A_.q = va; B_.q = vb;
#pragma unroll
            for (int j = 0; j < 8; ++j)
                Vt32[nxt][vd + j][wblk] = (unsigned)A_.u[j] | ((unsigned)B_.u[j] << 16);
        }
        __syncthreads();   // K[nxt] gll drained; V[nxt] visible; cur reads done
    }

    // ---- epilogue: O / l for both groups, bf16 store
    float invlA[4], invlB[4];
#pragma unroll
    for (int r = 0; r < 4; ++r) {
        invlA[r] = 1.f / __shfl(lA, quad * 4 + r);
        invlB[r] = 1.f / __shfl(lB, quad * 4 + r);
    }
    bf16* orowA = outb + (size_t)(b * NSEQ + m0 + wave * 16) * DIMM + h * DHEAD;
    bf16* orowB = orowA + (size_t)64 * DIMM;
#pragma unroll
    for (int dt = 0; dt < 4; ++dt)
#pragma unroll
        for (int r = 0; r < 4; ++r) {
            orowA[(size_t)(quad * 4 + r) * DIMM + dt * 16 + l16] =
                __float2bfloat16(accoA[dt][r] * invlA[r]);
            orowB[(size_t)(quad * 4 + r) * DIMM + dt * 16 + l16] =
                __float2bfloat16(accoB[dt][r] * invlB[r]);
        }
}

// ---------------------------------------------------------------- launch
extern "C" void kernel_launch(void* const* d_in, const int* in_sizes, int n_in,
                              void* d_out, int out_size, void* d_ws, size_t ws_size,
                              hipStream_t stream) {
    const float* x     = (const float*)d_in[0];
    const float* rpb   = (const float*)d_in[1];
    const float* W_qkv = (const float*)d_in[2];
    const float* W_out = (const float*)d_in[3];
    const float* b_out = (const float*)d_in[4];
    const float* ln_g  = (const float*)d_in[5];
    const float* ln_b  = (const float*)d_in[6];
    float* out = (float*)d_out;

    char* p = (char*)d_ws;
    bf16* xn    = (bf16*)p; p += (size_t)ROWS * DIMM * 2;
    bf16* qkv   = (bf16*)p; p += (size_t)ROWS * 3 * DIMM * 2;
    bf16* attn  = (bf16*)p; p += (size_t)ROWS * DIMM * 2;
    bf16* WqkvT = (bf16*)p; p += (size_t)3 * DIMM * DIMM * 2;
    bf16* WoutT = (bf16*)p; p += (size_t)DIMM * DIMM * 2;

    prep_kernel<<<ROWS + NT_QKV + NT_OUT, 256, 0, stream>>>(
        x, ln_g, ln_b, xn, W_qkv, WqkvT, W_out, WoutT);

    // 256x128 tiles: qkv grid 18x32 = 576 blocks, out grid 6x32 = 192 blocks
    gemm_mfma<true><<<dim3(3 * DIMM / 128, ROWS / 256), 512, 0, stream>>>(
        xn, WqkvT, nullptr, qkv, ROWS, 3 * DIMM, DIMM);

    attn_mfma<<<NBLK, 256, 0, stream>>>(qkv, rpb, attn);

    gemm_mfma<false><<<dim3(DIMM / 128, ROWS / 256), 512, 0, stream>>>(
        attn, WoutT, b_out, out, ROWS, DIMM, DIMM);
}